// Round 2
// baseline (5161.493 us; speedup 1.0000x reference)
//
#include <hip/hip_runtime.h>
#include <hip/hip_bf16.h>

#define BATCH 16
#define CH 256
#define HH 128
#define WW 128
#define HWSZ (HH * WW)
#define NHEAD 8
#define DHEAD 32
#define LDST 40   // LDS row stride in shorts (80B = 5x16B slots)

typedef __attribute__((ext_vector_type(8))) short bf16x8;
typedef __attribute__((ext_vector_type(4))) float f32x4;

__device__ __forceinline__ unsigned short f2b(float f) {
    unsigned u = __builtin_bit_cast(unsigned, f);
    u += 0x7fffu + ((u >> 16) & 1u);   // RNE
    return (unsigned short)(u >> 16);
}
__device__ __forceinline__ float blo(unsigned u) { return __builtin_bit_cast(float, u << 16); }
__device__ __forceinline__ float bhi(unsigned u) { return __builtin_bit_cast(float, u & 0xffff0000u); }

// ---------------------------------------------------------------------------
// Kernel 0: convert wq|wk|wv fp32 -> bf16, stashed at front of d_out.
// ---------------------------------------------------------------------------
__global__ __launch_bounds__(256)
void prep_kernel(const float* __restrict__ wq, const float* __restrict__ wk,
                 const float* __restrict__ wv, unsigned short* __restrict__ wb)
{
    const float* src = (blockIdx.y == 0) ? wq : (blockIdx.y == 1) ? wk : wv;
    unsigned short* dst = wb + blockIdx.y * 65536;
    int e = (blockIdx.x * 256 + threadIdx.x) * 8;
    const float4* s = reinterpret_cast<const float4*>(src + e);
    float4 a = s[0], c = s[1];
    uint4 u;
    u.x = (unsigned)f2b(a.x) | ((unsigned)f2b(a.y) << 16);
    u.y = (unsigned)f2b(a.z) | ((unsigned)f2b(a.w) << 16);
    u.z = (unsigned)f2b(c.x) | ((unsigned)f2b(c.y) << 16);
    u.w = (unsigned)f2b(c.z) | ((unsigned)f2b(c.w) << 16);
    *reinterpret_cast<uint4*>(dst + e) = u;
}

// ---------------------------------------------------------------------------
// Kernel 1: projections Y[b,h,p,d] = sum_c W[h*32+d,c] * X[b,c,p]   (bf16 out,
// pixel-major). BM=256 out channels, BN=64 px, BK=32.
// ---------------------------------------------------------------------------
__global__ __launch_bounds__(256)
void proj_kernel(const float* __restrict__ q, const float* __restrict__ k,
                 const float* __restrict__ v, const unsigned short* __restrict__ wb,
                 unsigned short* __restrict__ qh, unsigned short* __restrict__ kh,
                 unsigned short* __restrict__ vh)
{
    __shared__ __align__(16) unsigned short lA[256 * LDST];  // 20 KB [o][k]
    __shared__ __align__(16) unsigned short lB[64 * LDST];   //  5 KB [p][k]

    const int t = threadIdx.x;
    const int b = blockIdx.y;
    const int p0 = blockIdx.x * 64;

    const float* X; unsigned short* Y;
    if (blockIdx.z == 0)      { X = q; Y = qh; }
    else if (blockIdx.z == 1) { X = k; Y = kh; }
    else                      { X = v; Y = vh; }
    const unsigned short* Wb = wb + blockIdx.z * 65536;
    X += (size_t)b * CH * HWSZ;
    Y += (size_t)b * CH * HWSZ;   // CH*HWSZ == NHEAD*HWSZ*DHEAD

    const int lane = t & 63;
    const int wid  = t >> 6;
    const int lrow = lane & 15;
    const int lkg  = lane >> 4;
    const int pB = t & 63;
    const int cg = t >> 6;

    f32x4 acc[4][4];
    const f32x4 zero = {0.f, 0.f, 0.f, 0.f};
#pragma unroll
    for (int m = 0; m < 4; ++m)
#pragma unroll
        for (int n = 0; n < 4; ++n) acc[m][n] = zero;

    for (int ks = 0; ks < 8; ++ks) {
        const int k0 = ks * 32;
        // stage A: copy bf16 W tile (4 rounds x 16B)
#pragma unroll
        for (int r = 0; r < 4; ++r) {
            int idx = t + 256 * r;
            int o = idx >> 2, kc = idx & 3;
            uint4 wv4 = *reinterpret_cast<const uint4*>(Wb + o * 256 + k0 + kc * 8);
            *reinterpret_cast<uint4*>(&lA[o * LDST + kc * 8]) = wv4;
        }
        // stage B transposed: fp32 strided read + convert
        {
            const float* xp = X + (size_t)(k0 + cg * 8) * HWSZ + p0 + pB;
            float fv[8];
#pragma unroll
            for (int i = 0; i < 8; ++i) fv[i] = xp[(size_t)i * HWSZ];
            ushort4 h0, h1;
            h0.x = f2b(fv[0]); h0.y = f2b(fv[1]); h0.z = f2b(fv[2]); h0.w = f2b(fv[3]);
            h1.x = f2b(fv[4]); h1.y = f2b(fv[5]); h1.z = f2b(fv[6]); h1.w = f2b(fv[7]);
            *reinterpret_cast<ushort4*>(&lB[pB * LDST + cg * 8])     = h0;
            *reinterpret_cast<ushort4*>(&lB[pB * LDST + cg * 8 + 4]) = h1;
        }
        __syncthreads();

        bf16x8 af[4], bfv[4];
#pragma unroll
        for (int m = 0; m < 4; ++m)
            af[m] = *reinterpret_cast<const bf16x8*>(&lA[(wid * 64 + m * 16 + lrow) * LDST + lkg * 8]);
#pragma unroll
        for (int n = 0; n < 4; ++n)
            bfv[n] = *reinterpret_cast<const bf16x8*>(&lB[(n * 16 + lrow) * LDST + lkg * 8]);
#pragma unroll
        for (int m = 0; m < 4; ++m)
#pragma unroll
            for (int n = 0; n < 4; ++n)
                acc[m][n] = __builtin_amdgcn_mfma_f32_16x16x32_bf16(af[m], bfv[n], acc[m][n], 0, 0, 0);
        __syncthreads();
    }

    const int lr = lane >> 4, lc = lane & 15;
#pragma unroll
    for (int m = 0; m < 4; ++m)
#pragma unroll
        for (int n = 0; n < 4; ++n) {
            int o = wid * 64 + m * 16 + lr * 4;
            int hh_ = o >> 5, d0 = o & 31;
            int p = p0 + n * 16 + lc;
            ushort4 pk;
            pk.x = f2b(acc[m][n][0]); pk.y = f2b(acc[m][n][1]);
            pk.z = f2b(acc[m][n][2]); pk.w = f2b(acc[m][n][3]);
            *reinterpret_cast<ushort4*>(&Y[((size_t)hh_ * HWSZ + p) * DHEAD + d0]) = pk;
        }
}

// ---------------------------------------------------------------------------
// Kernel 2: local 5x5 attention. Pixel-major bf16 in/out. Single 32KB LDS
// buffer used twice (K phase, V phase). XOR slot swizzle kills py-parity
// bank conflicts.
// ---------------------------------------------------------------------------
__global__ __launch_bounds__(256, 4)
void attn_kernel(const unsigned short* __restrict__ qh, const unsigned short* __restrict__ kh,
                 const unsigned short* __restrict__ vh, unsigned short* __restrict__ ob)
{
    __shared__ __align__(16) unsigned short kv[400 * LDST];  // 32 KB

    const int t = threadIdx.x;
    const int b = blockIdx.z, h = blockIdx.y;
    const int x0 = (blockIdx.x & 7) * 16, y0 = (blockIdx.x >> 3) * 16;
    const size_t base = (size_t)(b * NHEAD + h) * HWSZ * DHEAD;

    const int px = t & 15, py = t >> 4;
    const int gx = x0 + px, gy = y0 + py;

    // Q -> f32 registers
    float qf[32];
    {
        const uint4* qp = reinterpret_cast<const uint4*>(qh + base + (size_t)(gy * WW + gx) * DHEAD);
#pragma unroll
        for (int c = 0; c < 4; ++c) {
            uint4 u = qp[c];
            qf[c*8+0] = blo(u.x); qf[c*8+1] = bhi(u.x);
            qf[c*8+2] = blo(u.y); qf[c*8+3] = bhi(u.y);
            qf[c*8+4] = blo(u.z); qf[c*8+5] = bhi(u.z);
            qf[c*8+6] = blo(u.w); qf[c*8+7] = bhi(u.w);
        }
    }

    auto stage = [&](const unsigned short* __restrict__ src) {
#pragma unroll
        for (int r = 0; r < 7; ++r) {
            int idx = t + 256 * r;
            if (idx < 1600) {
                int pos = idx >> 2, qc = idx & 3;
                int row = pos / 20;
                int col = pos - row * 20;
                int yy = y0 + row - 2, xx = x0 + col - 2;
                uint4 val = {0u, 0u, 0u, 0u};
                if ((unsigned)yy < HH && (unsigned)xx < WW)
                    val = *reinterpret_cast<const uint4*>(src + base + (size_t)(yy * WW + xx) * DHEAD + qc * 8);
                int slot = (qc ^ (pos & 3) ^ (row & 3)) & 3;
                *reinterpret_cast<uint4*>(&kv[pos * LDST + slot * 8]) = val;
            }
        }
    };

    stage(kh);
    __syncthreads();

    float ew[25];
#pragma unroll
    for (int wy = 0; wy < 5; ++wy) {
        const int row = py + wy;
#pragma unroll
        for (int wx = 0; wx < 5; ++wx) {
            const int cx = px + wx;
            const int addr0 = (row * 20 + cx) * LDST;
            const int M = (cx & 3) ^ (row & 3);
            float s0 = 0.f, s1 = 0.f, s2 = 0.f, s3 = 0.f;
#pragma unroll
            for (int qc = 0; qc < 4; ++qc) {
                const uint4 kk = *reinterpret_cast<const uint4*>(&kv[addr0 + ((qc ^ M) << 3)]);
                s0 += qf[qc*8+0] * blo(kk.x); s1 += qf[qc*8+1] * bhi(kk.x);
                s2 += qf[qc*8+2] * blo(kk.y); s3 += qf[qc*8+3] * bhi(kk.y);
                s0 += qf[qc*8+4] * blo(kk.z); s1 += qf[qc*8+5] * bhi(kk.z);
                s2 += qf[qc*8+6] * blo(kk.w); s3 += qf[qc*8+7] * bhi(kk.w);
            }
            // relu, /sqrt(32), exp (args >= 0 so no max-subtract needed)
            ew[wy*5+wx] = __expf(fmaxf((s0 + s1) + (s2 + s3), 0.f) * 0.17677669529663687f);
        }
    }
    float sum = 0.f;
#pragma unroll
    for (int i = 0; i < 25; ++i) sum += ew[i];
    const float inv = 1.f / sum;

    __syncthreads();
    stage(vh);
    __syncthreads();

    float acc[32];
#pragma unroll
    for (int d = 0; d < 32; ++d) acc[d] = 0.f;
#pragma unroll
    for (int wy = 0; wy < 5; ++wy) {
        const int row = py + wy;
#pragma unroll
        for (int wx = 0; wx < 5; ++wx) {
            const int cx = px + wx;
            const int addr0 = (row * 20 + cx) * LDST;
            const int M = (cx & 3) ^ (row & 3);
            const float w = ew[wy*5+wx];
#pragma unroll
            for (int qc = 0; qc < 4; ++qc) {
                const uint4 vv = *reinterpret_cast<const uint4*>(&kv[addr0 + ((qc ^ M) << 3)]);
                acc[qc*8+0] += w * blo(vv.x); acc[qc*8+1] += w * bhi(vv.x);
                acc[qc*8+2] += w * blo(vv.y); acc[qc*8+3] += w * bhi(vv.y);
                acc[qc*8+4] += w * blo(vv.z); acc[qc*8+5] += w * bhi(vv.z);
                acc[qc*8+6] += w * blo(vv.w); acc[qc*8+7] += w * bhi(vv.w);
            }
        }
    }

    unsigned short* op = ob + base + (size_t)(gy * WW + gx) * DHEAD;
#pragma unroll
    for (int c = 0; c < 4; ++c) {
        uint4 u;
        u.x = (unsigned)f2b(acc[c*8+0] * inv) | ((unsigned)f2b(acc[c*8+1] * inv) << 16);
        u.y = (unsigned)f2b(acc[c*8+2] * inv) | ((unsigned)f2b(acc[c*8+3] * inv) << 16);
        u.z = (unsigned)f2b(acc[c*8+4] * inv) | ((unsigned)f2b(acc[c*8+5] * inv) << 16);
        u.w = (unsigned)f2b(acc[c*8+6] * inv) | ((unsigned)f2b(acc[c*8+7] * inv) << 16);
        reinterpret_cast<uint4*>(op)[c] = u;
    }
}

// ---------------------------------------------------------------------------
// Kernel 3: o = wfc @ attn_out + residual, then LayerNorm over channels.
// ob is pixel-major so B-stage is one 16B load+write per thread per ks.
// ---------------------------------------------------------------------------
__global__ __launch_bounds__(256)
void fcln_kernel(const unsigned short* __restrict__ ob, const float* __restrict__ wfc,
                 const float* __restrict__ qres, const float* __restrict__ lnw,
                 const float* __restrict__ lnb, float* __restrict__ out)
{
    __shared__ __align__(16) unsigned short lA[256 * LDST];
    __shared__ __align__(16) unsigned short lB[64 * LDST];
    __shared__ float lsum[4][64];
    __shared__ float lssq[4][64];

    const int t = threadIdx.x;
    const int b = blockIdx.y;
    const int p0 = blockIdx.x * 64;

    const int lane = t & 63;
    const int wid  = t >> 6;
    const int lrow = lane & 15;
    const int lkg  = lane >> 4;
    const int pxs = t >> 2, qcs = t & 3;

    f32x4 acc[4][4];
    const f32x4 zero = {0.f, 0.f, 0.f, 0.f};
#pragma unroll
    for (int m = 0; m < 4; ++m)
#pragma unroll
        for (int n = 0; n < 4; ++n) acc[m][n] = zero;

    for (int ks = 0; ks < 8; ++ks) {
        const int k0 = ks * 32;
        // stage A: wfc fp32 -> bf16 (per-ks convert; cheap at this grid)
        {
            const float4* wr = reinterpret_cast<const float4*>(wfc + t * 256 + k0);
#pragma unroll
            for (int i = 0; i < 8; ++i) {
                float4 f = wr[i];
                ushort4 hh;
                hh.x = f2b(f.x); hh.y = f2b(f.y); hh.z = f2b(f.z); hh.w = f2b(f.w);
                *reinterpret_cast<ushort4*>(&lA[t * LDST + i * 4]) = hh;
            }
        }
        // stage B: head ks == channels k0..k0+32, pixel-major -> direct 16B
        {
            const unsigned short* obb = ob + (size_t)(b * NHEAD + ks) * HWSZ * DHEAD;
            uint4 bv = *reinterpret_cast<const uint4*>(obb + (size_t)(p0 + pxs) * DHEAD + qcs * 8);
            *reinterpret_cast<uint4*>(&lB[pxs * LDST + qcs * 8]) = bv;
        }
        __syncthreads();

        bf16x8 af[4], bfv[4];
#pragma unroll
        for (int m = 0; m < 4; ++m)
            af[m] = *reinterpret_cast<const bf16x8*>(&lA[(wid * 64 + m * 16 + lrow) * LDST + lkg * 8]);
#pragma unroll
        for (int n = 0; n < 4; ++n)
            bfv[n] = *reinterpret_cast<const bf16x8*>(&lB[(n * 16 + lrow) * LDST + lkg * 8]);
#pragma unroll
        for (int m = 0; m < 4; ++m)
#pragma unroll
            for (int n = 0; n < 4; ++n)
                acc[m][n] = __builtin_amdgcn_mfma_f32_16x16x32_bf16(af[m], bfv[n], acc[m][n], 0, 0, 0);
        __syncthreads();
    }

    // residual add
    const int lr = lane >> 4, lc = lane & 15;
    const float* qb = qres + (size_t)b * CH * HWSZ;
#pragma unroll
    for (int m = 0; m < 4; ++m)
#pragma unroll
        for (int n = 0; n < 4; ++n)
#pragma unroll
            for (int j = 0; j < 4; ++j) {
                int o = wid * 64 + m * 16 + lr * 4 + j;
                int p = p0 + n * 16 + lc;
                acc[m][n][j] += qb[(size_t)o * HWSZ + p];
            }

    // per-pixel LN partials
    float s[4], s2[4];
#pragma unroll
    for (int n = 0; n < 4; ++n) {
        float a = 0.f, c2 = 0.f;
#pragma unroll
        for (int m = 0; m < 4; ++m)
#pragma unroll
            for (int j = 0; j < 4; ++j) {
                float x = acc[m][n][j];
                a += x; c2 += x * x;
            }
        a  += __shfl_xor(a, 16);  a  += __shfl_xor(a, 32);
        c2 += __shfl_xor(c2, 16); c2 += __shfl_xor(c2, 32);
        s[n] = a; s2[n] = c2;
    }
    if (lane < 16) {
#pragma unroll
        for (int n = 0; n < 4; ++n) {
            lsum[wid][n * 16 + lane] = s[n];
            lssq[wid][n * 16 + lane] = s2[n];
        }
    }
    __syncthreads();

    float mu[4], rs[4];
#pragma unroll
    for (int n = 0; n < 4; ++n) {
        int p = n * 16 + lc;
        float ts = lsum[0][p] + lsum[1][p] + lsum[2][p] + lsum[3][p];
        float tq = lssq[0][p] + lssq[1][p] + lssq[2][p] + lssq[3][p];
        float m_ = ts * (1.f / 256.f);
        float v_ = tq * (1.f / 256.f) - m_ * m_;
        mu[n] = m_;
        rs[n] = rsqrtf(v_ + 1e-6f);
    }

    float* op = out + (size_t)b * CH * HWSZ;
#pragma unroll
    for (int m = 0; m < 4; ++m)
#pragma unroll
        for (int j = 0; j < 4; ++j) {
            int o = wid * 64 + m * 16 + lr * 4 + j;
            float g = lnw[o], bb = lnb[o];
#pragma unroll
            for (int n = 0; n < 4; ++n) {
                int p = p0 + n * 16 + lc;
                op[(size_t)o * HWSZ + p] = (acc[m][n][j] - mu[n]) * rs[n] * g + bb;
            }
        }
}

extern "C" void kernel_launch(void* const* d_in, const int* in_sizes, int n_in,
                              void* d_out, int out_size, void* d_ws, size_t ws_size,
                              hipStream_t stream) {
    const float* q   = (const float*)d_in[0];
    const float* k   = (const float*)d_in[1];
    const float* v   = (const float*)d_in[2];
    const float* wq  = (const float*)d_in[3];
    const float* wk  = (const float*)d_in[4];
    const float* wv  = (const float*)d_in[5];
    const float* wfc = (const float*)d_in[6];
    const float* lnw = (const float*)d_in[7];
    const float* lnb = (const float*)d_in[8];

    const size_t tsz = (size_t)BATCH * CH * HWSZ;
    if (ws_size < 4 * tsz * sizeof(unsigned short)) return;

    unsigned short* qh = (unsigned short*)d_ws;
    unsigned short* kh = qh + tsz;
    unsigned short* vh = kh + tsz;
    unsigned short* ob = vh + tsz;
    unsigned short* wb = (unsigned short*)d_out;  // 384KB stash; fcln overwrites later

    prep_kernel<<<dim3(32, 3), 256, 0, stream>>>(wq, wk, wv, wb);
    proj_kernel<<<dim3(HWSZ / 64, BATCH, 3), 256, 0, stream>>>(q, k, v, wb, qh, kh, vh);
    attn_kernel<<<dim3(64, NHEAD, BATCH), 256, 0, stream>>>(qh, kh, vh, ob);
    fcln_kernel<<<dim3(HWSZ / 64, BATCH), 256, 0, stream>>>(ob, wfc, q, lnw, lnb, (float*)d_out);
}

// Round 3
// 3003.628 us; speedup vs baseline: 1.7184x; 1.7184x over previous
//
#include <hip/hip_runtime.h>
#include <hip/hip_bf16.h>

#define BATCH 16
#define CH 256
#define HH 128
#define WW 128
#define HWSZ (HH * WW)
#define NHEAD 8
#define DHEAD 32
#define LDST 40   // LDS row stride in shorts (80B = 5x16B slots)

typedef __attribute__((ext_vector_type(8))) short bf16x8;
typedef __attribute__((ext_vector_type(4))) float f32x4;

__device__ __forceinline__ unsigned short f2b(float f) {
    unsigned u = __builtin_bit_cast(unsigned, f);
    u += 0x7fffu + ((u >> 16) & 1u);   // RNE
    return (unsigned short)(u >> 16);
}
__device__ __forceinline__ float blo(unsigned u) { return __builtin_bit_cast(float, u << 16); }
__device__ __forceinline__ float bhi(unsigned u) { return __builtin_bit_cast(float, u & 0xffff0000u); }

// ---------------------------------------------------------------------------
// Kernel 0: convert wq|wk|wv fp32 -> bf16, stashed at front of d_out.
// ---------------------------------------------------------------------------
__global__ __launch_bounds__(256)
void prep_kernel(const float* __restrict__ wq, const float* __restrict__ wk,
                 const float* __restrict__ wv, unsigned short* __restrict__ wb)
{
    const float* src = (blockIdx.y == 0) ? wq : (blockIdx.y == 1) ? wk : wv;
    unsigned short* dst = wb + blockIdx.y * 65536;
    int e = (blockIdx.x * 256 + threadIdx.x) * 8;
    const float4* s = reinterpret_cast<const float4*>(src + e);
    float4 a = s[0], c = s[1];
    uint4 u;
    u.x = (unsigned)f2b(a.x) | ((unsigned)f2b(a.y) << 16);
    u.y = (unsigned)f2b(a.z) | ((unsigned)f2b(a.w) << 16);
    u.z = (unsigned)f2b(c.x) | ((unsigned)f2b(c.y) << 16);
    u.w = (unsigned)f2b(c.z) | ((unsigned)f2b(c.w) << 16);
    *reinterpret_cast<uint4*>(dst + e) = u;
}

// ---------------------------------------------------------------------------
// Kernel 1: projections Y[b,h,p,d] = sum_c W[h*32+d,c] * X[b,c,p]   (bf16 out,
// pixel-major). BM=256 out channels, BN=64 px, BK=32.
// ---------------------------------------------------------------------------
__global__ __launch_bounds__(256)
void proj_kernel(const float* __restrict__ q, const float* __restrict__ k,
                 const float* __restrict__ v, const unsigned short* __restrict__ wb,
                 unsigned short* __restrict__ qh, unsigned short* __restrict__ kh,
                 unsigned short* __restrict__ vh)
{
    __shared__ __align__(16) unsigned short lA[256 * LDST];  // 20 KB [o][k]
    __shared__ __align__(16) unsigned short lB[64 * LDST];   //  5 KB [p][k]

    const int t = threadIdx.x;
    const int b = blockIdx.y;
    const int p0 = blockIdx.x * 64;

    const float* X; unsigned short* Y;
    if (blockIdx.z == 0)      { X = q; Y = qh; }
    else if (blockIdx.z == 1) { X = k; Y = kh; }
    else                      { X = v; Y = vh; }
    const unsigned short* Wb = wb + blockIdx.z * 65536;
    X += (size_t)b * CH * HWSZ;
    Y += (size_t)b * CH * HWSZ;   // CH*HWSZ == NHEAD*HWSZ*DHEAD

    const int lane = t & 63;
    const int wid  = t >> 6;
    const int lrow = lane & 15;
    const int lkg  = lane >> 4;
    const int pB = t & 63;
    const int cg = t >> 6;

    f32x4 acc[4][4];
    const f32x4 zero = {0.f, 0.f, 0.f, 0.f};
#pragma unroll
    for (int m = 0; m < 4; ++m)
#pragma unroll
        for (int n = 0; n < 4; ++n) acc[m][n] = zero;

    for (int ks = 0; ks < 8; ++ks) {
        const int k0 = ks * 32;
        // stage A: copy bf16 W tile (4 rounds x 16B)
#pragma unroll
        for (int r = 0; r < 4; ++r) {
            int idx = t + 256 * r;
            int o = idx >> 2, kc = idx & 3;
            uint4 wv4 = *reinterpret_cast<const uint4*>(Wb + o * 256 + k0 + kc * 8);
            *reinterpret_cast<uint4*>(&lA[o * LDST + kc * 8]) = wv4;
        }
        // stage B transposed: fp32 strided read + convert
        {
            const float* xp = X + (size_t)(k0 + cg * 8) * HWSZ + p0 + pB;
            float fv[8];
#pragma unroll
            for (int i = 0; i < 8; ++i) fv[i] = xp[(size_t)i * HWSZ];
            ushort4 h0, h1;
            h0.x = f2b(fv[0]); h0.y = f2b(fv[1]); h0.z = f2b(fv[2]); h0.w = f2b(fv[3]);
            h1.x = f2b(fv[4]); h1.y = f2b(fv[5]); h1.z = f2b(fv[6]); h1.w = f2b(fv[7]);
            *reinterpret_cast<ushort4*>(&lB[pB * LDST + cg * 8])     = h0;
            *reinterpret_cast<ushort4*>(&lB[pB * LDST + cg * 8 + 4]) = h1;
        }
        __syncthreads();

        bf16x8 af[4], bfv[4];
#pragma unroll
        for (int m = 0; m < 4; ++m)
            af[m] = *reinterpret_cast<const bf16x8*>(&lA[(wid * 64 + m * 16 + lrow) * LDST + lkg * 8]);
#pragma unroll
        for (int n = 0; n < 4; ++n)
            bfv[n] = *reinterpret_cast<const bf16x8*>(&lB[(n * 16 + lrow) * LDST + lkg * 8]);
#pragma unroll
        for (int m = 0; m < 4; ++m)
#pragma unroll
            for (int n = 0; n < 4; ++n)
                acc[m][n] = __builtin_amdgcn_mfma_f32_16x16x32_bf16(af[m], bfv[n], acc[m][n], 0, 0, 0);
        __syncthreads();
    }

    const int lr = lane >> 4, lc = lane & 15;
#pragma unroll
    for (int m = 0; m < 4; ++m)
#pragma unroll
        for (int n = 0; n < 4; ++n) {
            int o = wid * 64 + m * 16 + lr * 4;
            int hh_ = o >> 5, d0 = o & 31;
            int p = p0 + n * 16 + lc;
            ushort4 pk;
            pk.x = f2b(acc[m][n][0]); pk.y = f2b(acc[m][n][1]);
            pk.z = f2b(acc[m][n][2]); pk.w = f2b(acc[m][n][3]);
            *reinterpret_cast<ushort4*>(&Y[((size_t)hh_ * HWSZ + p) * DHEAD + d0]) = pk;
        }
}

// ---------------------------------------------------------------------------
// Kernel 2: local 5x5 attention. Pixel-major bf16 in/out. Single 32KB LDS
// buffer used twice (K phase, V phase). XOR slot swizzle (incl. the cx>>3
// bit that breaks the px<->px+8 same-bank pair).
// ---------------------------------------------------------------------------
__global__ __launch_bounds__(256)
void attn_kernel(const unsigned short* __restrict__ qh, const unsigned short* __restrict__ kh,
                 const unsigned short* __restrict__ vh, unsigned short* __restrict__ ob)
{
    __shared__ __align__(16) unsigned short kv[400 * LDST];  // 32 KB

    const int t = threadIdx.x;
    const int b = blockIdx.z, h = blockIdx.y;
    const int x0 = (blockIdx.x & 7) * 16, y0 = (blockIdx.x >> 3) * 16;
    const size_t base = (size_t)(b * NHEAD + h) * HWSZ * DHEAD;

    const int px = t & 15, py = t >> 4;
    const int gx = x0 + px, gy = y0 + py;

    // Q -> f32 registers
    float qf[32];
    {
        const uint4* qp = reinterpret_cast<const uint4*>(qh + base + (size_t)(gy * WW + gx) * DHEAD);
#pragma unroll
        for (int c = 0; c < 4; ++c) {
            uint4 u = qp[c];
            qf[c*8+0] = blo(u.x); qf[c*8+1] = bhi(u.x);
            qf[c*8+2] = blo(u.y); qf[c*8+3] = bhi(u.y);
            qf[c*8+4] = blo(u.z); qf[c*8+5] = bhi(u.z);
            qf[c*8+6] = blo(u.w); qf[c*8+7] = bhi(u.w);
        }
    }

    auto stage = [&](const unsigned short* __restrict__ src) {
#pragma unroll
        for (int r = 0; r < 7; ++r) {
            int idx = t + 256 * r;
            if (idx < 1600) {
                int pos = idx >> 2, qc = idx & 3;
                int row = pos / 20;
                int col = pos - row * 20;
                int yy = y0 + row - 2, xx = x0 + col - 2;
                uint4 val = {0u, 0u, 0u, 0u};
                if ((unsigned)yy < HH && (unsigned)xx < WW)
                    val = *reinterpret_cast<const uint4*>(src + base + (size_t)(yy * WW + xx) * DHEAD + qc * 8);
                int slot = (qc ^ (col & 3) ^ (row & 3) ^ ((col >> 3) & 1)) & 3;
                *reinterpret_cast<uint4*>(&kv[pos * LDST + slot * 8]) = val;
            }
        }
    };

    stage(kh);
    __syncthreads();

    float ew[25];
#pragma unroll
    for (int wy = 0; wy < 5; ++wy) {
        const int row = py + wy;
#pragma unroll
        for (int wx = 0; wx < 5; ++wx) {
            const int cx = px + wx;
            const int addr0 = (row * 20 + cx) * LDST;
            const int M = (cx & 3) ^ (row & 3) ^ ((cx >> 3) & 1);
            float s0 = 0.f, s1 = 0.f, s2 = 0.f, s3 = 0.f;
#pragma unroll
            for (int qc = 0; qc < 4; ++qc) {
                const uint4 kk = *reinterpret_cast<const uint4*>(&kv[addr0 + ((qc ^ M) << 3)]);
                s0 += qf[qc*8+0] * blo(kk.x); s1 += qf[qc*8+1] * bhi(kk.x);
                s2 += qf[qc*8+2] * blo(kk.y); s3 += qf[qc*8+3] * bhi(kk.y);
                s0 += qf[qc*8+4] * blo(kk.z); s1 += qf[qc*8+5] * bhi(kk.z);
                s2 += qf[qc*8+6] * blo(kk.w); s3 += qf[qc*8+7] * bhi(kk.w);
            }
            // relu, /sqrt(32), exp (args >= 0 so no max-subtract needed)
            ew[wy*5+wx] = __expf(fmaxf((s0 + s1) + (s2 + s3), 0.f) * 0.17677669529663687f);
        }
    }
    float sum = 0.f;
#pragma unroll
    for (int i = 0; i < 25; ++i) sum += ew[i];
    const float inv = 1.f / sum;

    __syncthreads();
    stage(vh);
    __syncthreads();

    float acc[32];
#pragma unroll
    for (int d = 0; d < 32; ++d) acc[d] = 0.f;
#pragma unroll
    for (int wy = 0; wy < 5; ++wy) {
        const int row = py + wy;
#pragma unroll
        for (int wx = 0; wx < 5; ++wx) {
            const int cx = px + wx;
            const int addr0 = (row * 20 + cx) * LDST;
            const int M = (cx & 3) ^ (row & 3) ^ ((cx >> 3) & 1);
            const float w = ew[wy*5+wx];
#pragma unroll
            for (int qc = 0; qc < 4; ++qc) {
                const uint4 vv = *reinterpret_cast<const uint4*>(&kv[addr0 + ((qc ^ M) << 3)]);
                acc[qc*8+0] += w * blo(vv.x); acc[qc*8+1] += w * bhi(vv.x);
                acc[qc*8+2] += w * blo(vv.y); acc[qc*8+3] += w * bhi(vv.y);
                acc[qc*8+4] += w * blo(vv.z); acc[qc*8+5] += w * bhi(vv.z);
                acc[qc*8+6] += w * blo(vv.w); acc[qc*8+7] += w * bhi(vv.w);
            }
        }
    }

    unsigned short* op = ob + base + (size_t)(gy * WW + gx) * DHEAD;
#pragma unroll
    for (int c = 0; c < 4; ++c) {
        uint4 u;
        u.x = (unsigned)f2b(acc[c*8+0] * inv) | ((unsigned)f2b(acc[c*8+1] * inv) << 16);
        u.y = (unsigned)f2b(acc[c*8+2] * inv) | ((unsigned)f2b(acc[c*8+3] * inv) << 16);
        u.z = (unsigned)f2b(acc[c*8+4] * inv) | ((unsigned)f2b(acc[c*8+5] * inv) << 16);
        u.w = (unsigned)f2b(acc[c*8+6] * inv) | ((unsigned)f2b(acc[c*8+7] * inv) << 16);
        reinterpret_cast<uint4*>(op)[c] = u;
    }
}

// ---------------------------------------------------------------------------
// Kernel 3: o = wfc @ attn_out + residual, then LayerNorm over channels.
// ob is pixel-major so B-stage is one 16B load+write per thread per ks.
// ---------------------------------------------------------------------------
__global__ __launch_bounds__(256)
void fcln_kernel(const unsigned short* __restrict__ ob, const float* __restrict__ wfc,
                 const float* __restrict__ qres, const float* __restrict__ lnw,
                 const float* __restrict__ lnb, float* __restrict__ out)
{
    __shared__ __align__(16) unsigned short lA[256 * LDST];
    __shared__ __align__(16) unsigned short lB[64 * LDST];
    __shared__ float lsum[4][64];
    __shared__ float lssq[4][64];

    const int t = threadIdx.x;
    const int b = blockIdx.y;
    const int p0 = blockIdx.x * 64;

    const int lane = t & 63;
    const int wid  = t >> 6;
    const int lrow = lane & 15;
    const int lkg  = lane >> 4;
    const int pxs = t >> 2, qcs = t & 3;

    f32x4 acc[4][4];
    const f32x4 zero = {0.f, 0.f, 0.f, 0.f};
#pragma unroll
    for (int m = 0; m < 4; ++m)
#pragma unroll
        for (int n = 0; n < 4; ++n) acc[m][n] = zero;

    for (int ks = 0; ks < 8; ++ks) {
        const int k0 = ks * 32;
        // stage A: wfc fp32 -> bf16 (per-ks convert; cheap at this grid)
        {
            const float4* wr = reinterpret_cast<const float4*>(wfc + t * 256 + k0);
#pragma unroll
            for (int i = 0; i < 8; ++i) {
                float4 f = wr[i];
                ushort4 hh;
                hh.x = f2b(f.x); hh.y = f2b(f.y); hh.z = f2b(f.z); hh.w = f2b(f.w);
                *reinterpret_cast<ushort4*>(&lA[t * LDST + i * 4]) = hh;
            }
        }
        // stage B: head ks == channels k0..k0+32, pixel-major -> direct 16B
        {
            const unsigned short* obb = ob + (size_t)(b * NHEAD + ks) * HWSZ * DHEAD;
            uint4 bv = *reinterpret_cast<const uint4*>(obb + (size_t)(p0 + pxs) * DHEAD + qcs * 8);
            *reinterpret_cast<uint4*>(&lB[pxs * LDST + qcs * 8]) = bv;
        }
        __syncthreads();

        bf16x8 af[4], bfv[4];
#pragma unroll
        for (int m = 0; m < 4; ++m)
            af[m] = *reinterpret_cast<const bf16x8*>(&lA[(wid * 64 + m * 16 + lrow) * LDST + lkg * 8]);
#pragma unroll
        for (int n = 0; n < 4; ++n)
            bfv[n] = *reinterpret_cast<const bf16x8*>(&lB[(n * 16 + lrow) * LDST + lkg * 8]);
#pragma unroll
        for (int m = 0; m < 4; ++m)
#pragma unroll
            for (int n = 0; n < 4; ++n)
                acc[m][n] = __builtin_amdgcn_mfma_f32_16x16x32_bf16(af[m], bfv[n], acc[m][n], 0, 0, 0);
        __syncthreads();
    }

    // residual add
    const int lr = lane >> 4, lc = lane & 15;
    const float* qb = qres + (size_t)b * CH * HWSZ;
#pragma unroll
    for (int m = 0; m < 4; ++m)
#pragma unroll
        for (int n = 0; n < 4; ++n)
#pragma unroll
            for (int j = 0; j < 4; ++j) {
                int o = wid * 64 + m * 16 + lr * 4 + j;
                int p = p0 + n * 16 + lc;
                acc[m][n][j] += qb[(size_t)o * HWSZ + p];
            }

    // per-pixel LN partials
    float s[4], s2[4];
#pragma unroll
    for (int n = 0; n < 4; ++n) {
        float a = 0.f, c2 = 0.f;
#pragma unroll
        for (int m = 0; m < 4; ++m)
#pragma unroll
            for (int j = 0; j < 4; ++j) {
                float x = acc[m][n][j];
                a += x; c2 += x * x;
            }
        a  += __shfl_xor(a, 16);  a  += __shfl_xor(a, 32);
        c2 += __shfl_xor(c2, 16); c2 += __shfl_xor(c2, 32);
        s[n] = a; s2[n] = c2;
    }
    if (lane < 16) {
#pragma unroll
        for (int n = 0; n < 4; ++n) {
            lsum[wid][n * 16 + lane] = s[n];
            lssq[wid][n * 16 + lane] = s2[n];
        }
    }
    __syncthreads();

    float mu[4], rs[4];
#pragma unroll
    for (int n = 0; n < 4; ++n) {
        int p = n * 16 + lc;
        float ts = lsum[0][p] + lsum[1][p] + lsum[2][p] + lsum[3][p];
        float tq = lssq[0][p] + lssq[1][p] + lssq[2][p] + lssq[3][p];
        float m_ = ts * (1.f / 256.f);
        float v_ = tq * (1.f / 256.f) - m_ * m_;
        mu[n] = m_;
        rs[n] = rsqrtf(v_ + 1e-6f);
    }

    float* op = out + (size_t)b * CH * HWSZ;
#pragma unroll
    for (int m = 0; m < 4; ++m)
#pragma unroll
        for (int j = 0; j < 4; ++j) {
            int o = wid * 64 + m * 16 + lr * 4 + j;
            float g = lnw[o], bb = lnb[o];
#pragma unroll
            for (int n = 0; n < 4; ++n) {
                int p = p0 + n * 16 + lc;
                op[(size_t)o * HWSZ + p] = (acc[m][n][j] - mu[n]) * rs[n] * g + bb;
            }
        }
}

extern "C" void kernel_launch(void* const* d_in, const int* in_sizes, int n_in,
                              void* d_out, int out_size, void* d_ws, size_t ws_size,
                              hipStream_t stream) {
    const float* q   = (const float*)d_in[0];
    const float* k   = (const float*)d_in[1];
    const float* v   = (const float*)d_in[2];
    const float* wq  = (const float*)d_in[3];
    const float* wk  = (const float*)d_in[4];
    const float* wv  = (const float*)d_in[5];
    const float* wfc = (const float*)d_in[6];
    const float* lnw = (const float*)d_in[7];
    const float* lnb = (const float*)d_in[8];

    const size_t tsz = (size_t)BATCH * CH * HWSZ;
    if (ws_size < 4 * tsz * sizeof(unsigned short)) return;

    unsigned short* qh = (unsigned short*)d_ws;
    unsigned short* kh = qh + tsz;
    unsigned short* vh = kh + tsz;
    unsigned short* ob = vh + tsz;
    unsigned short* wb = (unsigned short*)d_out;  // 384KB stash; fcln overwrites later

    prep_kernel<<<dim3(32, 3), 256, 0, stream>>>(wq, wk, wv, wb);
    proj_kernel<<<dim3(HWSZ / 64, BATCH, 3), 256, 0, stream>>>(q, k, v, wb, qh, kh, vh);
    attn_kernel<<<dim3(64, NHEAD, BATCH), 256, 0, stream>>>(qh, kh, vh, ob);
    fcln_kernel<<<dim3(HWSZ / 64, BATCH), 256, 0, stream>>>(ob, wfc, q, lnw, lnb, (float*)d_out);
}

// Round 4
// 1592.134 us; speedup vs baseline: 3.2419x; 1.8865x over previous
//
#include <hip/hip_runtime.h>
#include <hip/hip_bf16.h>

#define BATCH 16
#define CH 256
#define HH 128
#define WW 128
#define HWSZ (HH * WW)
#define NHEAD 8
#define DHEAD 32
#define LDST 40      // LDS row stride in shorts for GEMM tiles (80B)
#define PW 132       // padded spatial width  (2 halo each side)
#define PPIX (132 * 132)

typedef __attribute__((ext_vector_type(8))) short bf16x8;
typedef __attribute__((ext_vector_type(4))) float f32x4;
typedef _Float16 h2v __attribute__((ext_vector_type(2)));

__device__ __forceinline__ unsigned short f2b(float f) {
    unsigned u = __builtin_bit_cast(unsigned, f);
    u += 0x7fffu + ((u >> 16) & 1u);   // RNE
    return (unsigned short)(u >> 16);
}
__device__ __forceinline__ unsigned short f2h(float f) {
    _Float16 h = (_Float16)f;
    return __builtin_bit_cast(unsigned short, h);
}

#if __has_builtin(__builtin_amdgcn_fdot2)
#define DOT2(a, b, c) __builtin_amdgcn_fdot2((a), (b), (c), false)
#else
#define DOT2(a, b, c) ((c) + (float)(a).x * (float)(b).x + (float)(a).y * (float)(b).y)
#endif

// ---------------------------------------------------------------------------
// Kernel Z: zero the spatial border of padded K/V buffers (1040 px per b,h).
// ---------------------------------------------------------------------------
__global__ __launch_bounds__(256)
void zpad_kernel(unsigned short* __restrict__ kpad, unsigned short* __restrict__ vpad)
{
    int bid = blockIdx.x;  // 0..255 : (bh, tensor)
    unsigned short* dst = ((bid & 1) ? vpad : kpad) + (size_t)(bid >> 1) * PPIX * DHEAD;
    const uint4 z = {0u, 0u, 0u, 0u};
    for (int i = threadIdx.x; i < 1040; i += 256) {
        int row, col;
        if (i < 264)      { row = i / 132; col = i - row * 132; }
        else if (i < 528) { int j = i - 264; int r = j / 132; row = 130 + r; col = j - r * 132; }
        else              { int j = i - 528; row = 2 + (j >> 2); int c = j & 3; col = (c < 2) ? c : (128 + c); }
        uint4* p = reinterpret_cast<uint4*>(dst + (size_t)(row * PW + col) * DHEAD);
        p[0] = z; p[1] = z; p[2] = z; p[3] = z;
    }
}

// ---------------------------------------------------------------------------
// Kernel 0: convert wq|wk|wv fp32 -> bf16, stashed at front of d_out.
// ---------------------------------------------------------------------------
__global__ __launch_bounds__(256)
void prep_kernel(const float* __restrict__ wq, const float* __restrict__ wk,
                 const float* __restrict__ wv, unsigned short* __restrict__ wb)
{
    const float* src = (blockIdx.y == 0) ? wq : (blockIdx.y == 1) ? wk : wv;
    unsigned short* dst = wb + blockIdx.y * 65536;
    int e = (blockIdx.x * 256 + threadIdx.x) * 8;
    const float4* s = reinterpret_cast<const float4*>(src + e);
    float4 a = s[0], c = s[1];
    uint4 u;
    u.x = (unsigned)f2b(a.x) | ((unsigned)f2b(a.y) << 16);
    u.y = (unsigned)f2b(a.z) | ((unsigned)f2b(a.w) << 16);
    u.z = (unsigned)f2b(c.x) | ((unsigned)f2b(c.y) << 16);
    u.w = (unsigned)f2b(c.z) | ((unsigned)f2b(c.w) << 16);
    *reinterpret_cast<uint4*>(dst + e) = u;
}

// ---------------------------------------------------------------------------
// Kernel 1: projections -> f16, pixel-major. q unpadded; k,v spatially padded.
// ---------------------------------------------------------------------------
__global__ __launch_bounds__(256)
void proj_kernel(const float* __restrict__ q, const float* __restrict__ k,
                 const float* __restrict__ v, const unsigned short* __restrict__ wb,
                 unsigned short* __restrict__ qh, unsigned short* __restrict__ kpad,
                 unsigned short* __restrict__ vpad)
{
    __shared__ __align__(16) unsigned short lA[256 * LDST];  // 20 KB [o][k]
    __shared__ __align__(16) unsigned short lB[64 * LDST];   //  5 KB [p][k]

    const int t = threadIdx.x;
    const int b = blockIdx.y;
    const int p0 = blockIdx.x * 64;
    const int z = blockIdx.z;

    const float* X; unsigned short* Y;
    if (z == 0)      { X = q; Y = qh; }
    else if (z == 1) { X = k; Y = kpad; }
    else             { X = v; Y = vpad; }
    const unsigned short* Wb = wb + z * 65536;
    X += (size_t)b * CH * HWSZ;
    const size_t pixstride = (z == 0) ? (size_t)HWSZ : (size_t)PPIX;
    Y += (size_t)b * NHEAD * pixstride * DHEAD;

    const int lane = t & 63;
    const int wid  = t >> 6;
    const int lrow = lane & 15;
    const int lkg  = lane >> 4;
    const int pB = t & 63;
    const int cg = t >> 6;

    f32x4 acc[4][4];
    const f32x4 zero = {0.f, 0.f, 0.f, 0.f};
#pragma unroll
    for (int m = 0; m < 4; ++m)
#pragma unroll
        for (int n = 0; n < 4; ++n) acc[m][n] = zero;

    for (int ks = 0; ks < 8; ++ks) {
        const int k0 = ks * 32;
#pragma unroll
        for (int r = 0; r < 4; ++r) {
            int idx = t + 256 * r;
            int o = idx >> 2, kc = idx & 3;
            uint4 wv4 = *reinterpret_cast<const uint4*>(Wb + o * 256 + k0 + kc * 8);
            *reinterpret_cast<uint4*>(&lA[o * LDST + kc * 8]) = wv4;
        }
        {
            const float* xp = X + (size_t)(k0 + cg * 8) * HWSZ + p0 + pB;
            float fv[8];
#pragma unroll
            for (int i = 0; i < 8; ++i) fv[i] = xp[(size_t)i * HWSZ];
            ushort4 h0, h1;
            h0.x = f2b(fv[0]); h0.y = f2b(fv[1]); h0.z = f2b(fv[2]); h0.w = f2b(fv[3]);
            h1.x = f2b(fv[4]); h1.y = f2b(fv[5]); h1.z = f2b(fv[6]); h1.w = f2b(fv[7]);
            *reinterpret_cast<ushort4*>(&lB[pB * LDST + cg * 8])     = h0;
            *reinterpret_cast<ushort4*>(&lB[pB * LDST + cg * 8 + 4]) = h1;
        }
        __syncthreads();

        bf16x8 af[4], bfv[4];
#pragma unroll
        for (int m = 0; m < 4; ++m)
            af[m] = *reinterpret_cast<const bf16x8*>(&lA[(wid * 64 + m * 16 + lrow) * LDST + lkg * 8]);
#pragma unroll
        for (int n = 0; n < 4; ++n)
            bfv[n] = *reinterpret_cast<const bf16x8*>(&lB[(n * 16 + lrow) * LDST + lkg * 8]);
#pragma unroll
        for (int m = 0; m < 4; ++m)
#pragma unroll
            for (int n = 0; n < 4; ++n)
                acc[m][n] = __builtin_amdgcn_mfma_f32_16x16x32_bf16(af[m], bfv[n], acc[m][n], 0, 0, 0);
        __syncthreads();
    }

    const int lr = lane >> 4, lc = lane & 15;
#pragma unroll
    for (int m = 0; m < 4; ++m)
#pragma unroll
        for (int n = 0; n < 4; ++n) {
            int o = wid * 64 + m * 16 + lr * 4;
            int hh_ = o >> 5, d0 = o & 31;
            int p = p0 + n * 16 + lc;
            ushort4 pk;
            pk.x = f2h(acc[m][n][0]); pk.y = f2h(acc[m][n][1]);
            pk.z = f2h(acc[m][n][2]); pk.w = f2h(acc[m][n][3]);
            size_t pix;
            if (z == 0) pix = (size_t)hh_ * HWSZ + p;
            else { int row = p >> 7, col = p & 127; pix = (size_t)hh_ * PPIX + (size_t)(row + 2) * PW + (col + 2); }
            *reinterpret_cast<ushort4*>(&Y[pix * DHEAD + d0]) = pk;
        }
}

// ---------------------------------------------------------------------------
// Kernel 2: local 5x5 attention — NO LDS, pure cached gather from padded K/V.
// f16 throughout: corr via v_dot2_f32_f16, PV via packed f16 fma with
// pre-normalized weights. Output written in place over qh.
// ---------------------------------------------------------------------------
__global__ __launch_bounds__(256)
void attn_kernel(unsigned short* __restrict__ qh,
                 const unsigned short* __restrict__ kpad,
                 const unsigned short* __restrict__ vpad)
{
    const int t = threadIdx.x;
    const int bh = blockIdx.z * NHEAD + blockIdx.y;
    const int x0 = (blockIdx.x & 7) * 16, y0 = (blockIdx.x >> 3) * 16;
    const int px = t & 15, py = t >> 4;
    const int gx = x0 + px, gy = y0 + py;

    unsigned short* qp = qh + ((size_t)bh * HWSZ + gy * WW + gx) * DHEAD;
    const unsigned short* kb = kpad + (size_t)bh * PPIX * DHEAD;
    const unsigned short* vb = vpad + (size_t)bh * PPIX * DHEAD;

    union { uint4 u4[4]; h2v h2[16]; } Q;
#pragma unroll
    for (int c = 0; c < 4; ++c) Q.u4[c] = reinterpret_cast<const uint4*>(qp)[c];

    float ew[25];
#pragma unroll
    for (int wy = 0; wy < 5; ++wy) {
        const unsigned short* krow = kb + (size_t)((gy + wy) * PW + gx) * DHEAD;
#pragma unroll
        for (int wx = 0; wx < 5; ++wx) {
            float s = 0.f;
#pragma unroll
            for (int qc = 0; qc < 4; ++qc) {
                union { uint4 u; h2v h2[4]; } K;
                K.u = *reinterpret_cast<const uint4*>(krow + wx * DHEAD + qc * 8);
#pragma unroll
                for (int j = 0; j < 4; ++j)
                    s = DOT2(Q.h2[qc * 4 + j], K.h2[j], s);
            }
            ew[wy * 5 + wx] = __expf(fmaxf(s, 0.f) * 0.17677669529663687f);
        }
        __builtin_amdgcn_sched_barrier(0);
    }

    float sum = 0.f;
#pragma unroll
    for (int i = 0; i < 25; ++i) sum += ew[i];
    const float inv = 1.f / sum;

    union { uint4 u4[4]; h2v h2[16]; } A;
    const h2v hz = {(_Float16)0.f, (_Float16)0.f};
#pragma unroll
    for (int i = 0; i < 16; ++i) A.h2[i] = hz;

#pragma unroll
    for (int wy = 0; wy < 5; ++wy) {
        const unsigned short* vrow = vb + (size_t)((gy + wy) * PW + gx) * DHEAD;
#pragma unroll
        for (int wx = 0; wx < 5; ++wx) {
            _Float16 wh = (_Float16)(ew[wy * 5 + wx] * inv);   // normalized: partials stay O(1)
            h2v w2 = {wh, wh};
#pragma unroll
            for (int qc = 0; qc < 4; ++qc) {
                union { uint4 u; h2v h2[4]; } V;
                V.u = *reinterpret_cast<const uint4*>(vrow + wx * DHEAD + qc * 8);
#pragma unroll
                for (int j = 0; j < 4; ++j)
                    A.h2[qc * 4 + j] += w2 * V.h2[j];          // v_pk_fma_f16
            }
        }
        __builtin_amdgcn_sched_barrier(0);
    }

#pragma unroll
    for (int c = 0; c < 4; ++c)
        reinterpret_cast<uint4*>(qp)[c] = A.u4[c];
}

// ---------------------------------------------------------------------------
// Kernel 3: o = wfc @ attn_out + residual, then LayerNorm over channels.
// attn_out (f16, pixel-major, in qh) -> bf16 in stage.
// ---------------------------------------------------------------------------
__global__ __launch_bounds__(256)
void fcln_kernel(const unsigned short* __restrict__ ob, const float* __restrict__ wfc,
                 const float* __restrict__ qres, const float* __restrict__ lnw,
                 const float* __restrict__ lnb, float* __restrict__ out)
{
    __shared__ __align__(16) unsigned short lA[256 * LDST];
    __shared__ __align__(16) unsigned short lB[64 * LDST];
    __shared__ float lsum[4][64];
    __shared__ float lssq[4][64];

    const int t = threadIdx.x;
    const int b = blockIdx.y;
    const int p0 = blockIdx.x * 64;

    const int lane = t & 63;
    const int wid  = t >> 6;
    const int lrow = lane & 15;
    const int lkg  = lane >> 4;
    const int pxs = t >> 2, qcs = t & 3;

    f32x4 acc[4][4];
    const f32x4 zero = {0.f, 0.f, 0.f, 0.f};
#pragma unroll
    for (int m = 0; m < 4; ++m)
#pragma unroll
        for (int n = 0; n < 4; ++n) acc[m][n] = zero;

    for (int ks = 0; ks < 8; ++ks) {
        const int k0 = ks * 32;
        {
            const float4* wr = reinterpret_cast<const float4*>(wfc + t * 256 + k0);
#pragma unroll
            for (int i = 0; i < 8; ++i) {
                float4 f = wr[i];
                ushort4 hh;
                hh.x = f2b(f.x); hh.y = f2b(f.y); hh.z = f2b(f.z); hh.w = f2b(f.w);
                *reinterpret_cast<ushort4*>(&lA[t * LDST + i * 4]) = hh;
            }
        }
        {
            const unsigned short* obb = ob + (size_t)(b * NHEAD + ks) * HWSZ * DHEAD;
            uint4 bv = *reinterpret_cast<const uint4*>(obb + (size_t)(p0 + pxs) * DHEAD + qcs * 8);
            // f16 -> bf16
            uint4 o4;
            {
                h2v h;
                h = __builtin_bit_cast(h2v, bv.x); o4.x = (unsigned)f2b((float)h.x) | ((unsigned)f2b((float)h.y) << 16);
                h = __builtin_bit_cast(h2v, bv.y); o4.y = (unsigned)f2b((float)h.x) | ((unsigned)f2b((float)h.y) << 16);
                h = __builtin_bit_cast(h2v, bv.z); o4.z = (unsigned)f2b((float)h.x) | ((unsigned)f2b((float)h.y) << 16);
                h = __builtin_bit_cast(h2v, bv.w); o4.w = (unsigned)f2b((float)h.x) | ((unsigned)f2b((float)h.y) << 16);
            }
            *reinterpret_cast<uint4*>(&lB[pxs * LDST + qcs * 8]) = o4;
        }
        __syncthreads();

        bf16x8 af[4], bfv[4];
#pragma unroll
        for (int m = 0; m < 4; ++m)
            af[m] = *reinterpret_cast<const bf16x8*>(&lA[(wid * 64 + m * 16 + lrow) * LDST + lkg * 8]);
#pragma unroll
        for (int n = 0; n < 4; ++n)
            bfv[n] = *reinterpret_cast<const bf16x8*>(&lB[(n * 16 + lrow) * LDST + lkg * 8]);
#pragma unroll
        for (int m = 0; m < 4; ++m)
#pragma unroll
            for (int n = 0; n < 4; ++n)
                acc[m][n] = __builtin_amdgcn_mfma_f32_16x16x32_bf16(af[m], bfv[n], acc[m][n], 0, 0, 0);
        __syncthreads();
    }

    const int lr = lane >> 4, lc = lane & 15;
    const float* qb = qres + (size_t)b * CH * HWSZ;
#pragma unroll
    for (int m = 0; m < 4; ++m)
#pragma unroll
        for (int n = 0; n < 4; ++n)
#pragma unroll
            for (int j = 0; j < 4; ++j) {
                int o = wid * 64 + m * 16 + lr * 4 + j;
                int p = p0 + n * 16 + lc;
                acc[m][n][j] += qb[(size_t)o * HWSZ + p];
            }

    float s[4], s2[4];
#pragma unroll
    for (int n = 0; n < 4; ++n) {
        float a = 0.f, c2 = 0.f;
#pragma unroll
        for (int m = 0; m < 4; ++m)
#pragma unroll
            for (int j = 0; j < 4; ++j) {
                float x = acc[m][n][j];
                a += x; c2 += x * x;
            }
        a  += __shfl_xor(a, 16);  a  += __shfl_xor(a, 32);
        c2 += __shfl_xor(c2, 16); c2 += __shfl_xor(c2, 32);
        s[n] = a; s2[n] = c2;
    }
    if (lane < 16) {
#pragma unroll
        for (int n = 0; n < 4; ++n) {
            lsum[wid][n * 16 + lane] = s[n];
            lssq[wid][n * 16 + lane] = s2[n];
        }
    }
    __syncthreads();

    float mu[4], rs[4];
#pragma unroll
    for (int n = 0; n < 4; ++n) {
        int p = n * 16 + lc;
        float ts = lsum[0][p] + lsum[1][p] + lsum[2][p] + lsum[3][p];
        float tq = lssq[0][p] + lssq[1][p] + lssq[2][p] + lssq[3][p];
        float m_ = ts * (1.f / 256.f);
        float v_ = tq * (1.f / 256.f) - m_ * m_;
        mu[n] = m_;
        rs[n] = rsqrtf(v_ + 1e-6f);
    }

    float* op = out + (size_t)b * CH * HWSZ;
#pragma unroll
    for (int m = 0; m < 4; ++m)
#pragma unroll
        for (int j = 0; j < 4; ++j) {
            int o = wid * 64 + m * 16 + lr * 4 + j;
            float g = lnw[o], bb = lnb[o];
#pragma unroll
            for (int n = 0; n < 4; ++n) {
                int p = p0 + n * 16 + lc;
                op[(size_t)o * HWSZ + p] = (acc[m][n][j] - mu[n]) * rs[n] * g + bb;
            }
        }
}

extern "C" void kernel_launch(void* const* d_in, const int* in_sizes, int n_in,
                              void* d_out, int out_size, void* d_ws, size_t ws_size,
                              hipStream_t stream) {
    const float* q   = (const float*)d_in[0];
    const float* k   = (const float*)d_in[1];
    const float* v   = (const float*)d_in[2];
    const float* wq  = (const float*)d_in[3];
    const float* wk  = (const float*)d_in[4];
    const float* wv  = (const float*)d_in[5];
    const float* wfc = (const float*)d_in[6];
    const float* lnw = (const float*)d_in[7];
    const float* lnb = (const float*)d_in[8];

    const size_t qsz = (size_t)BATCH * NHEAD * HWSZ * DHEAD;   // 67,108,864
    const size_t psz = (size_t)BATCH * NHEAD * PPIX * DHEAD;   // 71,368,704
    if (ws_size < (qsz + 2 * psz) * sizeof(unsigned short)) return;

    unsigned short* qh = (unsigned short*)d_ws;   // q proj, then attn output (in place)
    unsigned short* kp = qh + qsz;
    unsigned short* vp = kp + psz;
    unsigned short* wb = (unsigned short*)d_out;  // 384KB bf16 weight stash; fcln overwrites later

    zpad_kernel<<<256, 256, 0, stream>>>(kp, vp);
    prep_kernel<<<dim3(32, 3), 256, 0, stream>>>(wq, wk, wv, wb);
    proj_kernel<<<dim3(HWSZ / 64, BATCH, 3), 256, 0, stream>>>(q, k, v, wb, qh, kp, vp);
    attn_kernel<<<dim3(64, NHEAD, BATCH), 256, 0, stream>>>(qh, kp, vp);
    fcln_kernel<<<dim3(HWSZ / 64, BATCH), 256, 0, stream>>>(qh, wfc, q, lnw, lnb, (float*)d_out);
}

// Round 5
// 1542.057 us; speedup vs baseline: 3.3471x; 1.0325x over previous
//
#include <hip/hip_runtime.h>
#include <hip/hip_bf16.h>

#define BATCH 16
#define CH 256
#define HH 128
#define WW 128
#define HWSZ (HH * WW)
#define NHEAD 8
#define DHEAD 32
#define LDST 40      // LDS row stride in shorts for GEMM tiles (80B)
#define PW 132       // padded spatial width  (2 halo each side)
#define PPIX (132 * 132)

typedef __attribute__((ext_vector_type(8))) short bf16x8;
typedef __attribute__((ext_vector_type(4))) float f32x4;
typedef _Float16 h2v __attribute__((ext_vector_type(2)));

__device__ __forceinline__ unsigned short f2b(float f) {
    unsigned u = __builtin_bit_cast(unsigned, f);
    u += 0x7fffu + ((u >> 16) & 1u);   // RNE
    return (unsigned short)(u >> 16);
}
__device__ __forceinline__ unsigned short f2h(float f) {
    _Float16 h = (_Float16)f;
    return __builtin_bit_cast(unsigned short, h);
}

#if __has_builtin(__builtin_amdgcn_fdot2)
#define DOT2(a, b, c) __builtin_amdgcn_fdot2((a), (b), (c), false)
#else
#define DOT2(a, b, c) ((c) + (float)(a).x * (float)(b).x + (float)(a).y * (float)(b).y)
#endif

// ---------------------------------------------------------------------------
// Kernel Z: zero the spatial border of padded K/V buffers (1040 px per b,h).
// ---------------------------------------------------------------------------
__global__ __launch_bounds__(256)
void zpad_kernel(unsigned short* __restrict__ kpad, unsigned short* __restrict__ vpad)
{
    int bid = blockIdx.x;  // 0..255 : (bh, tensor)
    unsigned short* dst = ((bid & 1) ? vpad : kpad) + (size_t)(bid >> 1) * PPIX * DHEAD;
    const uint4 z = {0u, 0u, 0u, 0u};
    for (int i = threadIdx.x; i < 1040; i += 256) {
        int row, col;
        if (i < 264)      { row = i / 132; col = i - row * 132; }
        else if (i < 528) { int j = i - 264; int r = j / 132; row = 130 + r; col = j - r * 132; }
        else              { int j = i - 528; row = 2 + (j >> 2); int c = j & 3; col = (c < 2) ? c : (128 + c); }
        uint4* p = reinterpret_cast<uint4*>(dst + (size_t)(row * PW + col) * DHEAD);
        p[0] = z; p[1] = z; p[2] = z; p[3] = z;
    }
}

// ---------------------------------------------------------------------------
// Kernel 0: convert wq|wk|wv fp32 -> bf16, stashed at front of d_out.
// ---------------------------------------------------------------------------
__global__ __launch_bounds__(256)
void prep_kernel(const float* __restrict__ wq, const float* __restrict__ wk,
                 const float* __restrict__ wv, unsigned short* __restrict__ wb)
{
    const float* src = (blockIdx.y == 0) ? wq : (blockIdx.y == 1) ? wk : wv;
    unsigned short* dst = wb + blockIdx.y * 65536;
    int e = (blockIdx.x * 256 + threadIdx.x) * 8;
    const float4* s = reinterpret_cast<const float4*>(src + e);
    float4 a = s[0], c = s[1];
    uint4 u;
    u.x = (unsigned)f2b(a.x) | ((unsigned)f2b(a.y) << 16);
    u.y = (unsigned)f2b(a.z) | ((unsigned)f2b(a.w) << 16);
    u.z = (unsigned)f2b(c.x) | ((unsigned)f2b(c.y) << 16);
    u.w = (unsigned)f2b(c.z) | ((unsigned)f2b(c.w) << 16);
    *reinterpret_cast<uint4*>(dst + e) = u;
}

// ---------------------------------------------------------------------------
// Kernel 1: projections -> f16, pixel-major. q unpadded; k,v spatially padded.
// ---------------------------------------------------------------------------
__global__ __launch_bounds__(256)
void proj_kernel(const float* __restrict__ q, const float* __restrict__ k,
                 const float* __restrict__ v, const unsigned short* __restrict__ wb,
                 unsigned short* __restrict__ qh, unsigned short* __restrict__ kpad,
                 unsigned short* __restrict__ vpad)
{
    __shared__ __align__(16) unsigned short lA[256 * LDST];  // 20 KB [o][k]
    __shared__ __align__(16) unsigned short lB[64 * LDST];   //  5 KB [p][k]

    const int t = threadIdx.x;
    const int b = blockIdx.y;
    const int p0 = blockIdx.x * 64;
    const int z = blockIdx.z;

    const float* X; unsigned short* Y;
    if (z == 0)      { X = q; Y = qh; }
    else if (z == 1) { X = k; Y = kpad; }
    else             { X = v; Y = vpad; }
    const unsigned short* Wb = wb + z * 65536;
    X += (size_t)b * CH * HWSZ;
    const size_t pixstride = (z == 0) ? (size_t)HWSZ : (size_t)PPIX;
    Y += (size_t)b * NHEAD * pixstride * DHEAD;

    const int lane = t & 63;
    const int wid  = t >> 6;
    const int lrow = lane & 15;
    const int lkg  = lane >> 4;
    const int pB = t & 63;
    const int cg = t >> 6;

    f32x4 acc[4][4];
    const f32x4 zero = {0.f, 0.f, 0.f, 0.f};
#pragma unroll
    for (int m = 0; m < 4; ++m)
#pragma unroll
        for (int n = 0; n < 4; ++n) acc[m][n] = zero;

    for (int ks = 0; ks < 8; ++ks) {
        const int k0 = ks * 32;
#pragma unroll
        for (int r = 0; r < 4; ++r) {
            int idx = t + 256 * r;
            int o = idx >> 2, kc = idx & 3;
            uint4 wv4 = *reinterpret_cast<const uint4*>(Wb + o * 256 + k0 + kc * 8);
            *reinterpret_cast<uint4*>(&lA[o * LDST + kc * 8]) = wv4;
        }
        {
            const float* xp = X + (size_t)(k0 + cg * 8) * HWSZ + p0 + pB;
            float fv[8];
#pragma unroll
            for (int i = 0; i < 8; ++i) fv[i] = xp[(size_t)i * HWSZ];
            ushort4 h0, h1;
            h0.x = f2b(fv[0]); h0.y = f2b(fv[1]); h0.z = f2b(fv[2]); h0.w = f2b(fv[3]);
            h1.x = f2b(fv[4]); h1.y = f2b(fv[5]); h1.z = f2b(fv[6]); h1.w = f2b(fv[7]);
            *reinterpret_cast<ushort4*>(&lB[pB * LDST + cg * 8])     = h0;
            *reinterpret_cast<ushort4*>(&lB[pB * LDST + cg * 8 + 4]) = h1;
        }
        __syncthreads();

        bf16x8 af[4], bfv[4];
#pragma unroll
        for (int m = 0; m < 4; ++m)
            af[m] = *reinterpret_cast<const bf16x8*>(&lA[(wid * 64 + m * 16 + lrow) * LDST + lkg * 8]);
#pragma unroll
        for (int n = 0; n < 4; ++n)
            bfv[n] = *reinterpret_cast<const bf16x8*>(&lB[(n * 16 + lrow) * LDST + lkg * 8]);
#pragma unroll
        for (int m = 0; m < 4; ++m)
#pragma unroll
            for (int n = 0; n < 4; ++n)
                acc[m][n] = __builtin_amdgcn_mfma_f32_16x16x32_bf16(af[m], bfv[n], acc[m][n], 0, 0, 0);
        __syncthreads();
    }

    const int lr = lane >> 4, lc = lane & 15;
#pragma unroll
    for (int m = 0; m < 4; ++m)
#pragma unroll
        for (int n = 0; n < 4; ++n) {
            int o = wid * 64 + m * 16 + lr * 4;
            int hh_ = o >> 5, d0 = o & 31;
            int p = p0 + n * 16 + lc;
            ushort4 pk;
            pk.x = f2h(acc[m][n][0]); pk.y = f2h(acc[m][n][1]);
            pk.z = f2h(acc[m][n][2]); pk.w = f2h(acc[m][n][3]);
            size_t pix;
            if (z == 0) pix = (size_t)hh_ * HWSZ + p;
            else { int row = p >> 7, col = p & 127; pix = (size_t)hh_ * PPIX + (size_t)(row + 2) * PW + (col + 2); }
            *reinterpret_cast<ushort4*>(&Y[pix * DHEAD + d0]) = pk;
        }
}

// ---------------------------------------------------------------------------
// Kernel 2: local 5x5 attention — NO LDS, cached gather from padded K/V.
// XCD-swizzled 1D grid: each XCD owns contiguous bh-planes in raster tile
// order -> halo reuse stays in its L2. Output written in place over qh.
// ---------------------------------------------------------------------------
__global__ __launch_bounds__(256)
void attn_kernel(unsigned short* __restrict__ qh,
                 const unsigned short* __restrict__ kpad,
                 const unsigned short* __restrict__ vpad)
{
    const int t = threadIdx.x;
    // bijective XCD swizzle: 8192 blocks, 1024 per XCD (8192 % 8 == 0)
    const int swz = (blockIdx.x & 7) * 1024 + (blockIdx.x >> 3);
    const int bh = swz >> 6;           // 0..127 : b*8 + h
    const int tile = swz & 63;
    const int x0 = (tile & 7) * 16, y0 = (tile >> 3) * 16;
    const int px = t & 15, py = t >> 4;
    const int gx = x0 + px, gy = y0 + py;

    unsigned short* qp = qh + ((size_t)bh * HWSZ + gy * WW + gx) * DHEAD;
    const unsigned short* kb = kpad + (size_t)bh * PPIX * DHEAD;
    const unsigned short* vb = vpad + (size_t)bh * PPIX * DHEAD;

    union { uint4 u4[4]; h2v h2[16]; } Q;
#pragma unroll
    for (int c = 0; c < 4; ++c) Q.u4[c] = reinterpret_cast<const uint4*>(qp)[c];

    float ew[25];
#pragma unroll
    for (int wy = 0; wy < 5; ++wy) {
        const unsigned short* krow = kb + (size_t)((gy + wy) * PW + gx) * DHEAD;
#pragma unroll
        for (int wx = 0; wx < 5; ++wx) {
            float s = 0.f;
#pragma unroll
            for (int qc = 0; qc < 4; ++qc) {
                union { uint4 u; h2v h2[4]; } K;
                K.u = *reinterpret_cast<const uint4*>(krow + wx * DHEAD + qc * 8);
#pragma unroll
                for (int j = 0; j < 4; ++j)
                    s = DOT2(Q.h2[qc * 4 + j], K.h2[j], s);
            }
            ew[wy * 5 + wx] = __expf(fmaxf(s, 0.f) * 0.17677669529663687f);
        }
    }

    float sum = 0.f;
#pragma unroll
    for (int i = 0; i < 25; ++i) sum += ew[i];
    const float inv = 1.f / sum;

    union { uint4 u4[4]; h2v h2[16]; } A;
    const h2v hz = {(_Float16)0.f, (_Float16)0.f};
#pragma unroll
    for (int i = 0; i < 16; ++i) A.h2[i] = hz;

#pragma unroll
    for (int wy = 0; wy < 5; ++wy) {
        const unsigned short* vrow = vb + (size_t)((gy + wy) * PW + gx) * DHEAD;
#pragma unroll
        for (int wx = 0; wx < 5; ++wx) {
            _Float16 wh = (_Float16)(ew[wy * 5 + wx] * inv);   // normalized: partials stay O(1)
            h2v w2 = {wh, wh};
#pragma unroll
            for (int qc = 0; qc < 4; ++qc) {
                union { uint4 u; h2v h2[4]; } V;
                V.u = *reinterpret_cast<const uint4*>(vrow + wx * DHEAD + qc * 8);
#pragma unroll
                for (int j = 0; j < 4; ++j)
                    A.h2[qc * 4 + j] += w2 * V.h2[j];          // v_pk_fma_f16
            }
        }
    }

#pragma unroll
    for (int c = 0; c < 4; ++c)
        reinterpret_cast<uint4*>(qp)[c] = A.u4[c];
}

// ---------------------------------------------------------------------------
// Kernel 3: o = wfc @ attn_out + residual, then LayerNorm over channels.
// attn_out (f16, pixel-major, in qh) -> bf16 in stage.
// ---------------------------------------------------------------------------
__global__ __launch_bounds__(256)
void fcln_kernel(const unsigned short* __restrict__ ob, const float* __restrict__ wfc,
                 const float* __restrict__ qres, const float* __restrict__ lnw,
                 const float* __restrict__ lnb, float* __restrict__ out)
{
    __shared__ __align__(16) unsigned short lA[256 * LDST];
    __shared__ __align__(16) unsigned short lB[64 * LDST];
    __shared__ float lsum[4][64];
    __shared__ float lssq[4][64];

    const int t = threadIdx.x;
    const int b = blockIdx.y;
    const int p0 = blockIdx.x * 64;

    const int lane = t & 63;
    const int wid  = t >> 6;
    const int lrow = lane & 15;
    const int lkg  = lane >> 4;
    const int pxs = t >> 2, qcs = t & 3;

    f32x4 acc[4][4];
    const f32x4 zero = {0.f, 0.f, 0.f, 0.f};
#pragma unroll
    for (int m = 0; m < 4; ++m)
#pragma unroll
        for (int n = 0; n < 4; ++n) acc[m][n] = zero;

    for (int ks = 0; ks < 8; ++ks) {
        const int k0 = ks * 32;
        {
            const float4* wr = reinterpret_cast<const float4*>(wfc + t * 256 + k0);
#pragma unroll
            for (int i = 0; i < 8; ++i) {
                float4 f = wr[i];
                ushort4 hh;
                hh.x = f2b(f.x); hh.y = f2b(f.y); hh.z = f2b(f.z); hh.w = f2b(f.w);
                *reinterpret_cast<ushort4*>(&lA[t * LDST + i * 4]) = hh;
            }
        }
        {
            const unsigned short* obb = ob + (size_t)(b * NHEAD + ks) * HWSZ * DHEAD;
            uint4 bv = *reinterpret_cast<const uint4*>(obb + (size_t)(p0 + pxs) * DHEAD + qcs * 8);
            // f16 -> bf16
            uint4 o4;
            {
                h2v h;
                h = __builtin_bit_cast(h2v, bv.x); o4.x = (unsigned)f2b((float)h.x) | ((unsigned)f2b((float)h.y) << 16);
                h = __builtin_bit_cast(h2v, bv.y); o4.y = (unsigned)f2b((float)h.x) | ((unsigned)f2b((float)h.y) << 16);
                h = __builtin_bit_cast(h2v, bv.z); o4.z = (unsigned)f2b((float)h.x) | ((unsigned)f2b((float)h.y) << 16);
                h = __builtin_bit_cast(h2v, bv.w); o4.w = (unsigned)f2b((float)h.x) | ((unsigned)f2b((float)h.y) << 16);
            }
            *reinterpret_cast<uint4*>(&lB[pxs * LDST + qcs * 8]) = o4;
        }
        __syncthreads();

        bf16x8 af[4], bfv[4];
#pragma unroll
        for (int m = 0; m < 4; ++m)
            af[m] = *reinterpret_cast<const bf16x8*>(&lA[(wid * 64 + m * 16 + lrow) * LDST + lkg * 8]);
#pragma unroll
        for (int n = 0; n < 4; ++n)
            bfv[n] = *reinterpret_cast<const bf16x8*>(&lB[(n * 16 + lrow) * LDST + lkg * 8]);
#pragma unroll
        for (int m = 0; m < 4; ++m)
#pragma unroll
            for (int n = 0; n < 4; ++n)
                acc[m][n] = __builtin_amdgcn_mfma_f32_16x16x32_bf16(af[m], bfv[n], acc[m][n], 0, 0, 0);
        __syncthreads();
    }

    const int lr = lane >> 4, lc = lane & 15;
    const float* qb = qres + (size_t)b * CH * HWSZ;
#pragma unroll
    for (int m = 0; m < 4; ++m)
#pragma unroll
        for (int n = 0; n < 4; ++n)
#pragma unroll
            for (int j = 0; j < 4; ++j) {
                int o = wid * 64 + m * 16 + lr * 4 + j;
                int p = p0 + n * 16 + lc;
                acc[m][n][j] += qb[(size_t)o * HWSZ + p];
            }

    float s[4], s2[4];
#pragma unroll
    for (int n = 0; n < 4; ++n) {
        float a = 0.f, c2 = 0.f;
#pragma unroll
        for (int m = 0; m < 4; ++m)
#pragma unroll
            for (int j = 0; j < 4; ++j) {
                float x = acc[m][n][j];
                a += x; c2 += x * x;
            }
        a  += __shfl_xor(a, 16);  a  += __shfl_xor(a, 32);
        c2 += __shfl_xor(c2, 16); c2 += __shfl_xor(c2, 32);
        s[n] = a; s2[n] = c2;
    }
    if (lane < 16) {
#pragma unroll
        for (int n = 0; n < 4; ++n) {
            lsum[wid][n * 16 + lane] = s[n];
            lssq[wid][n * 16 + lane] = s2[n];
        }
    }
    __syncthreads();

    float mu[4], rs[4];
#pragma unroll
    for (int n = 0; n < 4; ++n) {
        int p = n * 16 + lc;
        float ts = lsum[0][p] + lsum[1][p] + lsum[2][p] + lsum[3][p];
        float tq = lssq[0][p] + lssq[1][p] + lssq[2][p] + lssq[3][p];
        float m_ = ts * (1.f / 256.f);
        float v_ = tq * (1.f / 256.f) - m_ * m_;
        mu[n] = m_;
        rs[n] = rsqrtf(v_ + 1e-6f);
    }

    float* op = out + (size_t)b * CH * HWSZ;
#pragma unroll
    for (int m = 0; m < 4; ++m)
#pragma unroll
        for (int j = 0; j < 4; ++j) {
            int o = wid * 64 + m * 16 + lr * 4 + j;
            float g = lnw[o], bb = lnb[o];
#pragma unroll
            for (int n = 0; n < 4; ++n) {
                int p = p0 + n * 16 + lc;
                op[(size_t)o * HWSZ + p] = (acc[m][n][j] - mu[n]) * rs[n] * g + bb;
            }
        }
}

extern "C" void kernel_launch(void* const* d_in, const int* in_sizes, int n_in,
                              void* d_out, int out_size, void* d_ws, size_t ws_size,
                              hipStream_t stream) {
    const float* q   = (const float*)d_in[0];
    const float* k   = (const float*)d_in[1];
    const float* v   = (const float*)d_in[2];
    const float* wq  = (const float*)d_in[3];
    const float* wk  = (const float*)d_in[4];
    const float* wv  = (const float*)d_in[5];
    const float* wfc = (const float*)d_in[6];
    const float* lnw = (const float*)d_in[7];
    const float* lnb = (const float*)d_in[8];

    const size_t qsz = (size_t)BATCH * NHEAD * HWSZ * DHEAD;   // 67,108,864
    const size_t psz = (size_t)BATCH * NHEAD * PPIX * DHEAD;   // 71,368,704
    if (ws_size < (qsz + 2 * psz) * sizeof(unsigned short)) return;

    unsigned short* qh = (unsigned short*)d_ws;   // q proj, then attn output (in place)
    unsigned short* kp = qh + qsz;
    unsigned short* vp = kp + psz;
    unsigned short* wb = (unsigned short*)d_out;  // 384KB bf16 weight stash; fcln overwrites later

    zpad_kernel<<<256, 256, 0, stream>>>(kp, vp);
    prep_kernel<<<dim3(32, 3), 256, 0, stream>>>(wq, wk, wv, wb);
    proj_kernel<<<dim3(HWSZ / 64, BATCH, 3), 256, 0, stream>>>(q, k, v, wb, qh, kp, vp);
    attn_kernel<<<8192, 256, 0, stream>>>(qh, kp, vp);
    fcln_kernel<<<dim3(HWSZ / 64, BATCH), 256, 0, stream>>>(qh, wfc, q, lnw, lnb, (float*)d_out);
}

// Round 6
// 806.160 us; speedup vs baseline: 6.4026x; 1.9128x over previous
//
#include <hip/hip_runtime.h>
#include <hip/hip_bf16.h>

#define BATCH 16
#define CH 256
#define HH 128
#define WW 128
#define HWSZ (HH * WW)
#define NHEAD 8
#define DHEAD 32
#define LDST 40      // LDS row stride in shorts for GEMM tiles (80B)
#define PW 132       // padded spatial width  (2 halo each side)
#define PPIX (132 * 132)

typedef __attribute__((ext_vector_type(8))) short bf16x8;
typedef __attribute__((ext_vector_type(4))) float f32x4;
typedef _Float16 h2v __attribute__((ext_vector_type(2)));

__device__ __forceinline__ unsigned short f2b(float f) {
    unsigned u = __builtin_bit_cast(unsigned, f);
    u += 0x7fffu + ((u >> 16) & 1u);   // RNE
    return (unsigned short)(u >> 16);
}
__device__ __forceinline__ unsigned short f2h(float f) {
    _Float16 h = (_Float16)f;
    return __builtin_bit_cast(unsigned short, h);
}

#if __has_builtin(__builtin_amdgcn_fdot2)
#define DOT2(a, b, c) __builtin_amdgcn_fdot2((a), (b), (c), false)
#else
#define DOT2(a, b, c) ((c) + (float)(a).x * (float)(b).x + (float)(a).y * (float)(b).y)
#endif

// ---------------------------------------------------------------------------
// Kernel Z: zero the spatial border of padded K/V buffers (1040 px per b,h).
// ---------------------------------------------------------------------------
__global__ __launch_bounds__(256)
void zpad_kernel(unsigned short* __restrict__ kpad, unsigned short* __restrict__ vpad)
{
    int bid = blockIdx.x;  // 0..255 : (bh, tensor)
    unsigned short* dst = ((bid & 1) ? vpad : kpad) + (size_t)(bid >> 1) * PPIX * DHEAD;
    const uint4 z = {0u, 0u, 0u, 0u};
    for (int i = threadIdx.x; i < 1040; i += 256) {
        int row, col;
        if (i < 264)      { row = i / 132; col = i - row * 132; }
        else if (i < 528) { int j = i - 264; int r = j / 132; row = 130 + r; col = j - r * 132; }
        else              { int j = i - 528; row = 2 + (j >> 2); int c = j & 3; col = (c < 2) ? c : (128 + c); }
        uint4* p = reinterpret_cast<uint4*>(dst + (size_t)(row * PW + col) * DHEAD);
        p[0] = z; p[1] = z; p[2] = z; p[3] = z;
    }
}

// ---------------------------------------------------------------------------
// Kernel 0: convert wq|wk|wv fp32 -> bf16, stashed at front of d_out.
// ---------------------------------------------------------------------------
__global__ __launch_bounds__(256)
void prep_kernel(const float* __restrict__ wq, const float* __restrict__ wk,
                 const float* __restrict__ wv, unsigned short* __restrict__ wb)
{
    const float* src = (blockIdx.y == 0) ? wq : (blockIdx.y == 1) ? wk : wv;
    unsigned short* dst = wb + blockIdx.y * 65536;
    int e = (blockIdx.x * 256 + threadIdx.x) * 8;
    const float4* s = reinterpret_cast<const float4*>(src + e);
    float4 a = s[0], c = s[1];
    uint4 u;
    u.x = (unsigned)f2b(a.x) | ((unsigned)f2b(a.y) << 16);
    u.y = (unsigned)f2b(a.z) | ((unsigned)f2b(a.w) << 16);
    u.z = (unsigned)f2b(c.x) | ((unsigned)f2b(c.y) << 16);
    u.w = (unsigned)f2b(c.z) | ((unsigned)f2b(c.w) << 16);
    *reinterpret_cast<uint4*>(dst + e) = u;
}

// ---------------------------------------------------------------------------
// Kernel 1: projections -> f16, pixel-major. q unpadded; k,v spatially padded.
// ---------------------------------------------------------------------------
__global__ __launch_bounds__(256)
void proj_kernel(const float* __restrict__ q, const float* __restrict__ k,
                 const float* __restrict__ v, const unsigned short* __restrict__ wb,
                 unsigned short* __restrict__ qh, unsigned short* __restrict__ kpad,
                 unsigned short* __restrict__ vpad)
{
    __shared__ __align__(16) unsigned short lA[256 * LDST];  // 20 KB [o][k]
    __shared__ __align__(16) unsigned short lB[64 * LDST];   //  5 KB [p][k]

    const int t = threadIdx.x;
    const int b = blockIdx.y;
    const int p0 = blockIdx.x * 64;
    const int z = blockIdx.z;

    const float* X; unsigned short* Y;
    if (z == 0)      { X = q; Y = qh; }
    else if (z == 1) { X = k; Y = kpad; }
    else             { X = v; Y = vpad; }
    const unsigned short* Wb = wb + z * 65536;
    X += (size_t)b * CH * HWSZ;
    const size_t pixstride = (z == 0) ? (size_t)HWSZ : (size_t)PPIX;
    Y += (size_t)b * NHEAD * pixstride * DHEAD;

    const int lane = t & 63;
    const int wid  = t >> 6;
    const int lrow = lane & 15;
    const int lkg  = lane >> 4;
    const int pB = t & 63;
    const int cg = t >> 6;

    f32x4 acc[4][4];
    const f32x4 zero = {0.f, 0.f, 0.f, 0.f};
#pragma unroll
    for (int m = 0; m < 4; ++m)
#pragma unroll
        for (int n = 0; n < 4; ++n) acc[m][n] = zero;

    for (int ks = 0; ks < 8; ++ks) {
        const int k0 = ks * 32;
#pragma unroll
        for (int r = 0; r < 4; ++r) {
            int idx = t + 256 * r;
            int o = idx >> 2, kc = idx & 3;
            uint4 wv4 = *reinterpret_cast<const uint4*>(Wb + o * 256 + k0 + kc * 8);
            *reinterpret_cast<uint4*>(&lA[o * LDST + kc * 8]) = wv4;
        }
        {
            const float* xp = X + (size_t)(k0 + cg * 8) * HWSZ + p0 + pB;
            float fv[8];
#pragma unroll
            for (int i = 0; i < 8; ++i) fv[i] = xp[(size_t)i * HWSZ];
            ushort4 h0, h1;
            h0.x = f2b(fv[0]); h0.y = f2b(fv[1]); h0.z = f2b(fv[2]); h0.w = f2b(fv[3]);
            h1.x = f2b(fv[4]); h1.y = f2b(fv[5]); h1.z = f2b(fv[6]); h1.w = f2b(fv[7]);
            *reinterpret_cast<ushort4*>(&lB[pB * LDST + cg * 8])     = h0;
            *reinterpret_cast<ushort4*>(&lB[pB * LDST + cg * 8 + 4]) = h1;
        }
        __syncthreads();

        bf16x8 af[4], bfv[4];
#pragma unroll
        for (int m = 0; m < 4; ++m)
            af[m] = *reinterpret_cast<const bf16x8*>(&lA[(wid * 64 + m * 16 + lrow) * LDST + lkg * 8]);
#pragma unroll
        for (int n = 0; n < 4; ++n)
            bfv[n] = *reinterpret_cast<const bf16x8*>(&lB[(n * 16 + lrow) * LDST + lkg * 8]);
#pragma unroll
        for (int m = 0; m < 4; ++m)
#pragma unroll
            for (int n = 0; n < 4; ++n)
                acc[m][n] = __builtin_amdgcn_mfma_f32_16x16x32_bf16(af[m], bfv[n], acc[m][n], 0, 0, 0);
        __syncthreads();
    }

    const int lr = lane >> 4, lc = lane & 15;
#pragma unroll
    for (int m = 0; m < 4; ++m)
#pragma unroll
        for (int n = 0; n < 4; ++n) {
            int o = wid * 64 + m * 16 + lr * 4;
            int hh_ = o >> 5, d0 = o & 31;
            int p = p0 + n * 16 + lc;
            ushort4 pk;
            pk.x = f2h(acc[m][n][0]); pk.y = f2h(acc[m][n][1]);
            pk.z = f2h(acc[m][n][2]); pk.w = f2h(acc[m][n][3]);
            size_t pix;
            if (z == 0) pix = (size_t)hh_ * HWSZ + p;
            else { int row = p >> 7, col = p & 127; pix = (size_t)hh_ * PPIX + (size_t)(row + 2) * PW + (col + 2); }
            *reinterpret_cast<ushort4*>(&Y[pix * DHEAD + d0]) = pk;
        }
}

// ---------------------------------------------------------------------------
// Kernel 2: local 5x5 attention — 4 lanes per pixel (qc = t&3), so every
// K/V/Q access is a contiguous 1KB span per wave (16 lines, 4 lanes/line)
// instead of 64 scattered lines. Dot via dot2 partials + shfl_xor butterfly.
// 1024-thread blocks: one 16x16 tile; K slab (25.6KB) fits L1.
// ---------------------------------------------------------------------------
__global__ __launch_bounds__(1024)
void attn_kernel(unsigned short* __restrict__ qh,
                 const unsigned short* __restrict__ kpad,
                 const unsigned short* __restrict__ vpad)
{
    const int t = threadIdx.x;
    // bijective XCD swizzle: 8192 blocks, 1024 per XCD
    const int swz = (blockIdx.x & 7) * 1024 + (blockIdx.x >> 3);
    const int bh = swz >> 6;           // 0..127 : b*8 + h
    const int tile = swz & 63;
    const int x0 = (tile & 7) * 16, y0 = (tile >> 3) * 16;
    const int qc = t & 3;              // 16B quarter of the 64B pixel vector
    const int px = (t >> 2) & 15;
    const int py = t >> 6;
    const int gx = x0 + px, gy = y0 + py;

    unsigned short* qp = qh + ((size_t)bh * HWSZ + gy * WW + gx) * DHEAD + qc * 8;
    const unsigned short* kb = kpad + (size_t)bh * PPIX * DHEAD + qc * 8;
    const unsigned short* vb = vpad + (size_t)bh * PPIX * DHEAD + qc * 8;

    union { uint4 u; h2v h2[4]; } Q;
    Q.u = *reinterpret_cast<const uint4*>(qp);

    float ew[25];
#pragma unroll
    for (int wy = 0; wy < 5; ++wy) {
        const unsigned short* krow = kb + (size_t)((gy + wy) * PW + gx) * DHEAD;
#pragma unroll
        for (int wx = 0; wx < 5; ++wx) {
            union { uint4 u; h2v h2[4]; } K;
            K.u = *reinterpret_cast<const uint4*>(krow + wx * DHEAD);
            float s = 0.f;
#pragma unroll
            for (int j = 0; j < 4; ++j)
                s = DOT2(Q.h2[j], K.h2[j], s);
            // combine the 4 quarter-dots of this pixel (lanes qc=0..3)
            s += __shfl_xor(s, 1);
            s += __shfl_xor(s, 2);
            ew[wy * 5 + wx] = __expf(fmaxf(s, 0.f) * 0.17677669529663687f);
        }
    }

    float sum = 0.f;
#pragma unroll
    for (int i = 0; i < 25; ++i) sum += ew[i];
    const float inv = 1.f / sum;

    union { uint4 u; h2v h2[4]; } A;
    const h2v hz = {(_Float16)0.f, (_Float16)0.f};
#pragma unroll
    for (int j = 0; j < 4; ++j) A.h2[j] = hz;

#pragma unroll
    for (int wy = 0; wy < 5; ++wy) {
        const unsigned short* vrow = vb + (size_t)((gy + wy) * PW + gx) * DHEAD;
#pragma unroll
        for (int wx = 0; wx < 5; ++wx) {
            _Float16 wh = (_Float16)(ew[wy * 5 + wx] * inv);   // normalized: partials stay O(1)
            h2v w2 = {wh, wh};
            union { uint4 u; h2v h2[4]; } V;
            V.u = *reinterpret_cast<const uint4*>(vrow + wx * DHEAD);
#pragma unroll
            for (int j = 0; j < 4; ++j)
                A.h2[j] += w2 * V.h2[j];                       // v_pk_fma_f16
        }
    }

    *reinterpret_cast<uint4*>(qp) = A.u;
}

// ---------------------------------------------------------------------------
// Kernel 3: o = wfc @ attn_out + residual, then LayerNorm over channels.
// attn_out (f16, pixel-major, in qh) -> bf16 in stage.
// ---------------------------------------------------------------------------
__global__ __launch_bounds__(256)
void fcln_kernel(const unsigned short* __restrict__ ob, const float* __restrict__ wfc,
                 const float* __restrict__ qres, const float* __restrict__ lnw,
                 const float* __restrict__ lnb, float* __restrict__ out)
{
    __shared__ __align__(16) unsigned short lA[256 * LDST];
    __shared__ __align__(16) unsigned short lB[64 * LDST];
    __shared__ float lsum[4][64];
    __shared__ float lssq[4][64];

    const int t = threadIdx.x;
    const int b = blockIdx.y;
    const int p0 = blockIdx.x * 64;

    const int lane = t & 63;
    const int wid  = t >> 6;
    const int lrow = lane & 15;
    const int lkg  = lane >> 4;
    const int pxs = t >> 2, qcs = t & 3;

    f32x4 acc[4][4];
    const f32x4 zero = {0.f, 0.f, 0.f, 0.f};
#pragma unroll
    for (int m = 0; m < 4; ++m)
#pragma unroll
        for (int n = 0; n < 4; ++n) acc[m][n] = zero;

    for (int ks = 0; ks < 8; ++ks) {
        const int k0 = ks * 32;
        {
            const float4* wr = reinterpret_cast<const float4*>(wfc + t * 256 + k0);
#pragma unroll
            for (int i = 0; i < 8; ++i) {
                float4 f = wr[i];
                ushort4 hh;
                hh.x = f2b(f.x); hh.y = f2b(f.y); hh.z = f2b(f.z); hh.w = f2b(f.w);
                *reinterpret_cast<ushort4*>(&lA[t * LDST + i * 4]) = hh;
            }
        }
        {
            const unsigned short* obb = ob + (size_t)(b * NHEAD + ks) * HWSZ * DHEAD;
            uint4 bv = *reinterpret_cast<const uint4*>(obb + (size_t)(p0 + pxs) * DHEAD + qcs * 8);
            // f16 -> bf16
            uint4 o4;
            {
                h2v h;
                h = __builtin_bit_cast(h2v, bv.x); o4.x = (unsigned)f2b((float)h.x) | ((unsigned)f2b((float)h.y) << 16);
                h = __builtin_bit_cast(h2v, bv.y); o4.y = (unsigned)f2b((float)h.x) | ((unsigned)f2b((float)h.y) << 16);
                h = __builtin_bit_cast(h2v, bv.z); o4.z = (unsigned)f2b((float)h.x) | ((unsigned)f2b((float)h.y) << 16);
                h = __builtin_bit_cast(h2v, bv.w); o4.w = (unsigned)f2b((float)h.x) | ((unsigned)f2b((float)h.y) << 16);
            }
            *reinterpret_cast<uint4*>(&lB[pxs * LDST + qcs * 8]) = o4;
        }
        __syncthreads();

        bf16x8 af[4], bfv[4];
#pragma unroll
        for (int m = 0; m < 4; ++m)
            af[m] = *reinterpret_cast<const bf16x8*>(&lA[(wid * 64 + m * 16 + lrow) * LDST + lkg * 8]);
#pragma unroll
        for (int n = 0; n < 4; ++n)
            bfv[n] = *reinterpret_cast<const bf16x8*>(&lB[(n * 16 + lrow) * LDST + lkg * 8]);
#pragma unroll
        for (int m = 0; m < 4; ++m)
#pragma unroll
            for (int n = 0; n < 4; ++n)
                acc[m][n] = __builtin_amdgcn_mfma_f32_16x16x32_bf16(af[m], bfv[n], acc[m][n], 0, 0, 0);
        __syncthreads();
    }

    const int lr = lane >> 4, lc = lane & 15;
    const float* qb = qres + (size_t)b * CH * HWSZ;
#pragma unroll
    for (int m = 0; m < 4; ++m)
#pragma unroll
        for (int n = 0; n < 4; ++n)
#pragma unroll
            for (int j = 0; j < 4; ++j) {
                int o = wid * 64 + m * 16 + lr * 4 + j;
                int p = p0 + n * 16 + lc;
                acc[m][n][j] += qb[(size_t)o * HWSZ + p];
            }

    float s[4], s2[4];
#pragma unroll
    for (int n = 0; n < 4; ++n) {
        float a = 0.f, c2 = 0.f;
#pragma unroll
        for (int m = 0; m < 4; ++m)
#pragma unroll
            for (int j = 0; j < 4; ++j) {
                float x = acc[m][n][j];
                a += x; c2 += x * x;
            }
        a  += __shfl_xor(a, 16);  a  += __shfl_xor(a, 32);
        c2 += __shfl_xor(c2, 16); c2 += __shfl_xor(c2, 32);
        s[n] = a; s2[n] = c2;
    }
    if (lane < 16) {
#pragma unroll
        for (int n = 0; n < 4; ++n) {
            lsum[wid][n * 16 + lane] = s[n];
            lssq[wid][n * 16 + lane] = s2[n];
        }
    }
    __syncthreads();

    float mu[4], rs[4];
#pragma unroll
    for (int n = 0; n < 4; ++n) {
        int p = n * 16 + lc;
        float ts = lsum[0][p] + lsum[1][p] + lsum[2][p] + lsum[3][p];
        float tq = lssq[0][p] + lssq[1][p] + lssq[2][p] + lssq[3][p];
        float m_ = ts * (1.f / 256.f);
        float v_ = tq * (1.f / 256.f) - m_ * m_;
        mu[n] = m_;
        rs[n] = rsqrtf(v_ + 1e-6f);
    }

    float* op = out + (size_t)b * CH * HWSZ;
#pragma unroll
    for (int m = 0; m < 4; ++m)
#pragma unroll
        for (int j = 0; j < 4; ++j) {
            int o = wid * 64 + m * 16 + lr * 4 + j;
            float g = lnw[o], bb = lnb[o];
#pragma unroll
            for (int n = 0; n < 4; ++n) {
                int p = p0 + n * 16 + lc;
                op[(size_t)o * HWSZ + p] = (acc[m][n][j] - mu[n]) * rs[n] * g + bb;
            }
        }
}

extern "C" void kernel_launch(void* const* d_in, const int* in_sizes, int n_in,
                              void* d_out, int out_size, void* d_ws, size_t ws_size,
                              hipStream_t stream) {
    const float* q   = (const float*)d_in[0];
    const float* k   = (const float*)d_in[1];
    const float* v   = (const float*)d_in[2];
    const float* wq  = (const float*)d_in[3];
    const float* wk  = (const float*)d_in[4];
    const float* wv  = (const float*)d_in[5];
    const float* wfc = (const float*)d_in[6];
    const float* lnw = (const float*)d_in[7];
    const float* lnb = (const float*)d_in[8];

    const size_t qsz = (size_t)BATCH * NHEAD * HWSZ * DHEAD;   // 67,108,864
    const size_t psz = (size_t)BATCH * NHEAD * PPIX * DHEAD;   // 71,368,704
    if (ws_size < (qsz + 2 * psz) * sizeof(unsigned short)) return;

    unsigned short* qh = (unsigned short*)d_ws;   // q proj, then attn output (in place)
    unsigned short* kp = qh + qsz;
    unsigned short* vp = kp + psz;
    unsigned short* wb = (unsigned short*)d_out;  // 384KB bf16 weight stash; fcln overwrites later

    zpad_kernel<<<256, 256, 0, stream>>>(kp, vp);
    prep_kernel<<<dim3(32, 3), 256, 0, stream>>>(wq, wk, wv, wb);
    proj_kernel<<<dim3(HWSZ / 64, BATCH, 3), 256, 0, stream>>>(q, k, v, wb, qh, kp, vp);
    attn_kernel<<<8192, 1024, 0, stream>>>(qh, kp, vp);
    fcln_kernel<<<dim3(HWSZ / 64, BATCH), 256, 0, stream>>>(qh, wfc, q, lnw, lnb, (float*)d_out);
}